// Round 1
// baseline (2444.006 us; speedup 1.0000x reference)
//
#include <hip/hip_runtime.h>
#include <math.h>

#define B_SZ 4096
#define D_SZ 1024
#define H_SZ 1024
#define T_SZ 50

typedef _Float16 f16;
typedef __attribute__((ext_vector_type(8))) _Float16 f16x8;
typedef __attribute__((ext_vector_type(4))) _Float16 f16x4;
typedef __attribute__((ext_vector_type(4))) float f32x4;
typedef __attribute__((ext_vector_type(4))) float f4;

// fast activations: 1 v_exp + 1 v_rcp each; error ~1e-6, far below fp16 noise
__device__ __forceinline__ float fast_sigmoid(float x) {
    return 1.0f / (1.0f + __expf(-x));
}
__device__ __forceinline__ float fast_tanh(float x) {
    return 1.0f - 2.0f / (__expf(2.0f * x) + 1.0f);
}

// async global->LDS, 16 bytes per lane
__device__ __forceinline__ void gl_lds16(const void* g, void* l) {
    __builtin_amdgcn_global_load_lds(
        (const __attribute__((address_space(1))) unsigned int*)g,
        (__attribute__((address_space(3))) unsigned int*)l, 16, 0, 0);
}

// ---------------------------------------------------------------------------
// fp32 -> fp16 conversion (4 elems/thread; n divisible by 4)
__global__ __launch_bounds__(256) void conv_kernel(
        const float* __restrict__ s, f16* __restrict__ d, int n) {
    int i = (blockIdx.x * 256 + threadIdx.x) * 4;
    if (i < n) {
        f4 v = *(const f4*)&s[i];
        f16x4 o = {(f16)v[0], (f16)v[1], (f16)v[2], (f16)v[3]};
        *(f16x4*)&d[i] = o;
    }
}

// ---------------------------------------------------------------------------
// h0 = tanh(ev @ w_init^T + b_init) via fp16 MFMA.
// Tile 128(M) x 64(N), 4 waves 2x2, wave 64x32 (4 mi x 2 ni frags 16x16x32).
__global__ __launch_bounds__(256, 2) void h0_kernel(
        const f16* __restrict__ ev, const f16* __restrict__ wi,
        const float* __restrict__ b_init, f16* __restrict__ hh) {
    __shared__ __align__(16) f16 lds[6144];  // A 128x32 @0, B 64x32 @4096
    const int tid = threadIdx.x;
    const int lane = tid & 63, wave = tid >> 6;
    const int b0 = blockIdx.y * 128, j0 = blockIdx.x * 64;
    const int wm = wave >> 1, wn = wave & 1;
    const int lrow = lane & 15, quad = lane >> 4;

    const f16* gsrc[3];
    int lbase[3];
    {
        const int row16 = lane >> 2, part = lane & 3;
#pragma unroll
        for (int i = 0; i < 3; ++i) {
            int c = wave + 4 * i;
            if (c < 8) {
                gsrc[i] = ev + (size_t)(b0 + c * 16 + row16) * D_SZ + part * 8;
                lbase[i] = c * 512;
            } else {
                int cc = c - 8;
                gsrc[i] = wi + (size_t)(j0 + cc * 16 + row16) * D_SZ + part * 8;
                lbase[i] = 4096 + cc * 512;
            }
        }
    }

    int offA[4], offB[2];
#pragma unroll
    for (int mi = 0; mi < 4; ++mi)
        offA[mi] = (wm * 64 + mi * 16 + lrow) * 32 + quad * 8;
#pragma unroll
    for (int ni = 0; ni < 2; ++ni)
        offB[ni] = 4096 + (wn * 32 + ni * 16 + lrow) * 32 + quad * 8;

    f32x4 acc[4][2] = {};

    for (int k0 = 0; k0 < D_SZ; k0 += 32) {
        __syncthreads();
#pragma unroll
        for (int i = 0; i < 3; ++i)
            gl_lds16(gsrc[i] + k0, &lds[lbase[i]] + lane * 8);
        __syncthreads();
        f16x8 aa[4], bb[2];
#pragma unroll
        for (int mi = 0; mi < 4; ++mi) aa[mi] = *(const f16x8*)&lds[offA[mi]];
#pragma unroll
        for (int ni = 0; ni < 2; ++ni) bb[ni] = *(const f16x8*)&lds[offB[ni]];
#pragma unroll
        for (int mi = 0; mi < 4; ++mi)
#pragma unroll
            for (int ni = 0; ni < 2; ++ni)
                acc[mi][ni] = __builtin_amdgcn_mfma_f32_16x16x32_f16(
                    aa[mi], bb[ni], acc[mi][ni], 0, 0, 0);
    }

#pragma unroll
    for (int ni = 0; ni < 2; ++ni) {
        const int j = j0 + wn * 32 + ni * 16 + lrow;
        const float bj = b_init[j];
#pragma unroll
        for (int mi = 0; mi < 4; ++mi)
#pragma unroll
            for (int reg = 0; reg < 4; ++reg) {
                const int b = b0 + wm * 64 + mi * 16 + quad * 4 + reg;
                hh[(size_t)b * H_SZ + j] = (f16)tanhf(acc[mi][ni][reg] + bj);
            }
    }
}

// ---------------------------------------------------------------------------
// One GRU step v2: gh = h @ w_hh^T, fp16 MFMA.
// 256 threads = 4 waves (2M x 2N); tile 128(M) x 64j x 3gates (N=192).
// Wave tile 64(M) x 96(N): 24 MFMA : 10 ds_read_b128 per BK=32 slice.
// Pipeline: 3 LDS buffers, 2 tiles in flight, counted s_waitcnt vmcnt(5),
// ONE raw s_barrier per slice (no vmcnt(0) drain in main loop — T3/T4).
// LDS fragment reads XOR-swizzled (slot ^= (row>>1)&3) with the inverse
// permutation applied to the GLOBAL source (global_load_lds writes linearly),
// so ds_read_b128 is bank-conflict-free (T2 / m173 pattern).
// LDS: 3 x (A 128x32 + B 192x32) f16 = 60 KB -> 2 blocks/CU.
__global__ __launch_bounds__(256, 2) void step_kernel(
        const f16* __restrict__ hh, const f16* __restrict__ w,
        const float* __restrict__ b_hh, const float* __restrict__ w_ih,
        const float* __restrict__ b_ih, const float* __restrict__ w_out,
        const float* __restrict__ teach, f16* __restrict__ nhh,
        float* __restrict__ out, int t) {
    __shared__ __align__(16) f16 lds[30720];  // 3 buffers x 10240 elems
    const int tid = threadIdx.x;
    const int lane = tid & 63, wave = tid >> 6;
    const int wm = wave >> 1, wn = wave & 1;
    const int b0 = blockIdx.y * 128, j0 = blockIdx.x * 64;
    const int lrow = lane & 15, quad = lane >> 4;

    // staging: 20 chunks (A 8, B 12) of 16 rows x 32 cols (1 KB each);
    // 5 issues x 4 waves; chunk = issue*4 + wave. Global col pre-swizzled.
    const f16* gsrc[5];
    int lbase[5];
    {
        const int r16 = lane >> 2;
        const int c4 = ((lane & 3) ^ ((lane >> 3) & 3)) * 8;  // inverse swizzle
#pragma unroll
        for (int i = 0; i < 5; ++i) {
            const int c = i * 4 + wave;
            if (c < 8) {
                gsrc[i] = hh + (size_t)(b0 + c * 16 + r16) * H_SZ + c4;
            } else {
                const int gr = (c - 8) * 16 + r16;  // gate*64 + jj
                gsrc[i] = w + (size_t)((gr >> 6) * H_SZ + j0 + (gr & 63)) * H_SZ + c4;
            }
            lbase[i] = c * 512 + lane * 8;
        }
    }

    // swizzled read slot: quad ^ ((row_in_chunk>>1)&3); row_in_chunk == lrow
    const int swq = (quad ^ ((lrow >> 1) & 3)) * 8;
    int offA[4], offB[3][2];
#pragma unroll
    for (int mi = 0; mi < 4; ++mi)
        offA[mi] = (wm * 64 + mi * 16 + lrow) * 32 + swq;
#pragma unroll
    for (int g = 0; g < 3; ++g)
#pragma unroll
        for (int ni = 0; ni < 2; ++ni)
            offB[g][ni] = 4096 + (g * 64 + wn * 32 + ni * 16 + lrow) * 32 + swq;

    f32x4 acc[3][4][2] = {};

    auto issue = [&](int kt, int bufbase) {
#pragma unroll
        for (int i = 0; i < 5; ++i)
            gl_lds16(gsrc[i] + kt * 32, &lds[bufbase + lbase[i]]);
    };

    // One pipeline stage. vm: 5 in steady state (tile kt landed, kt+1 in
    // flight), 0 only on the last iteration. Single barrier per slice:
    // after it, (a) all waves' tile-kt loads have landed (each waited its
    // own vmcnt first), and (b) all waves' reads+MFMA of tile kt-1 are done
    // (program order), so buf (kt+2)%3 == (kt-1)%3 is free to overwrite.
    auto stage = [&](int rdbase, int isbase, int vm, bool dois, int ktnext) {
        if (vm == 5)
            asm volatile("s_waitcnt vmcnt(5)" ::: "memory");
        else
            asm volatile("s_waitcnt vmcnt(0)" ::: "memory");
        __builtin_amdgcn_s_barrier();
        asm volatile("" ::: "memory");  // fence: no mem op crosses the barrier
        if (dois) issue(ktnext, isbase);
        f16x8 aa[4], bbv[3][2];
#pragma unroll
        for (int mi = 0; mi < 4; ++mi)
            aa[mi] = *(const f16x8*)&lds[rdbase + offA[mi]];
#pragma unroll
        for (int g = 0; g < 3; ++g)
#pragma unroll
            for (int ni = 0; ni < 2; ++ni)
                bbv[g][ni] = *(const f16x8*)&lds[rdbase + offB[g][ni]];
        __builtin_amdgcn_s_setprio(1);
#pragma unroll
        for (int g = 0; g < 3; ++g)
#pragma unroll
            for (int mi = 0; mi < 4; ++mi)
#pragma unroll
                for (int ni = 0; ni < 2; ++ni)
                    acc[g][mi][ni] = __builtin_amdgcn_mfma_f32_16x16x32_f16(
                        aa[mi], bbv[g][ni], acc[g][mi][ni], 0, 0, 0);
        __builtin_amdgcn_s_setprio(0);
    };

    // prologue: 2 tiles in flight
    issue(0, 0);
    issue(1, 10240);
    int rd = 0, isb = 20480;
    for (int kt = 0; kt < 30; ++kt) {
        stage(rd, isb, 5, true, kt + 2);
        rd += 10240; if (rd == 30720) rd = 0;
        isb += 10240; if (isb == 30720) isb = 0;
    }
    stage(rd, 0, 5, false, 0);
    rd += 10240; if (rd == 30720) rd = 0;
    stage(rd, 0, 0, false, 0);

    // -------- fused epilogue: gates, h_next, delta partials --------
    float p0[4][4], p1[4][4];
#pragma unroll
    for (int mi = 0; mi < 4; ++mi)
#pragma unroll
        for (int reg = 0; reg < 4; ++reg) {
            const int b = b0 + wm * 64 + mi * 16 + quad * 4 + reg;
            if (t > 0) {
                p0[mi][reg] = teach[b * (T_SZ * 2) + (t - 1) * 2 + 0];
                p1[mi][reg] = teach[b * (T_SZ * 2) + (t - 1) * 2 + 1];
            } else {
                p0[mi][reg] = 0.f;
                p1[mi][reg] = 0.f;
            }
        }

    float s0[4][4] = {}, s1[4][4] = {};
#pragma unroll
    for (int ni = 0; ni < 2; ++ni) {
        const int j = j0 + wn * 32 + ni * 16 + lrow;
        const float wr0 = w_ih[(0 * H_SZ + j) * 2 + 0];
        const float wr1 = w_ih[(0 * H_SZ + j) * 2 + 1];
        const float wz0 = w_ih[(1 * H_SZ + j) * 2 + 0];
        const float wz1 = w_ih[(1 * H_SZ + j) * 2 + 1];
        const float wn0 = w_ih[(2 * H_SZ + j) * 2 + 0];
        const float wn1 = w_ih[(2 * H_SZ + j) * 2 + 1];
        const float br = b_ih[0 * H_SZ + j] + b_hh[0 * H_SZ + j];
        const float bz = b_ih[1 * H_SZ + j] + b_hh[1 * H_SZ + j];
        const float bn = b_ih[2 * H_SZ + j];
        const float hbn = b_hh[2 * H_SZ + j];
        const float wo0 = w_out[j], wo1 = w_out[H_SZ + j];
#pragma unroll
        for (int mi = 0; mi < 4; ++mi) {
#pragma unroll
            for (int reg = 0; reg < 4; ++reg) {
                const int b = b0 + wm * 64 + mi * 16 + quad * 4 + reg;
                const float hr = acc[0][mi][ni][reg];
                const float hz = acc[1][mi][ni][reg];
                const float hn_ = acc[2][mi][ni][reg] + hbn;
                const float xr = wr0 * p0[mi][reg] + wr1 * p1[mi][reg] + br;
                const float xz = wz0 * p0[mi][reg] + wz1 * p1[mi][reg] + bz;
                const float xn = wn0 * p0[mi][reg] + wn1 * p1[mi][reg] + bn;
                const float r = fast_sigmoid(xr + hr);
                const float z = fast_sigmoid(xz + hz);
                const float n = fast_tanh(xn + r * hn_);
                const size_t idx = (size_t)b * H_SZ + j;
                const float hold = (float)hh[idx];
                const float hnew = (1.0f - z) * n + z * hold;
                nhh[idx] = (f16)hnew;
                s0[mi][reg] += hnew * wo0;
                s1[mi][reg] += hnew * wo1;
            }
        }
    }
#pragma unroll
    for (int mi = 0; mi < 4; ++mi)
#pragma unroll
        for (int reg = 0; reg < 4; ++reg) {
            float a = s0[mi][reg], c = s1[mi][reg];
#pragma unroll
            for (int m = 1; m < 16; m <<= 1) {
                a += __shfl_xor(a, m);
                c += __shfl_xor(c, m);
            }
            if (lrow == 0) {
                const int b = b0 + wm * 64 + mi * 16 + quad * 4 + reg;
                atomicAdd(&out[b * (T_SZ * 2) + t * 2 + 0], a);
                atomicAdd(&out[b * (T_SZ * 2) + t * 2 + 1], c);
            }
        }
}

// ---------------------------------------------------------------------------
// pred_deltas += b_out; pred_pos = cumsum
__global__ __launch_bounds__(256) void final_kernel(
        float* __restrict__ out, float* __restrict__ pos,
        const float* __restrict__ b_out) {
    int idx = blockIdx.x * 256 + threadIdx.x;  // b*2 + c
    if (idx >= B_SZ * 2) return;
    int b = idx >> 1, c = idx & 1;
    float bc = b_out[c];
    float acc = 0.0f;
    for (int t = 0; t < T_SZ; ++t) {
        float d = out[b * (T_SZ * 2) + t * 2 + c] + bc;
        out[b * (T_SZ * 2) + t * 2 + c] = d;
        acc += d;
        pos[b * (T_SZ * 2) + t * 2 + c] = acc;
    }
}

// ---------------------------------------------------------------------------
extern "C" void kernel_launch(void* const* d_in, const int* in_sizes, int n_in,
                              void* d_out, int out_size, void* d_ws, size_t ws_size,
                              hipStream_t stream) {
    const float* ev     = (const float*)d_in[0];
    const float* teach  = (const float*)d_in[1];
    const float* w_init = (const float*)d_in[2];
    const float* b_init = (const float*)d_in[3];
    const float* w_ih   = (const float*)d_in[4];
    const float* w_hh   = (const float*)d_in[5];
    const float* b_ih   = (const float*)d_in[6];
    const float* b_hh   = (const float*)d_in[7];
    const float* w_out  = (const float*)d_in[8];
    const float* b_out  = (const float*)d_in[9];

    float* out = (float*)d_out;                  // pred_deltas (B,T,2)
    float* pos = out + (size_t)B_SZ * T_SZ * 2;  // pred_pos    (B,T,2)

    // ws layout (f16 units): hA (4M), hB (4M), w_hh (3M), w_init (1M).
    // ev_f16 (4M) aliases hB (consumed by h0 before hB is first written).
    f16* ws = (f16*)d_ws;
    f16* hA    = ws;
    f16* hB    = hA + (size_t)B_SZ * H_SZ;
    f16* whh   = hB + (size_t)B_SZ * H_SZ;
    f16* winit = whh + (size_t)3 * H_SZ * H_SZ;
    f16* evf   = hB;  // alias

    hipMemsetAsync(out, 0, (size_t)B_SZ * T_SZ * 2 * sizeof(float), stream);

    conv_kernel<<<(3 * H_SZ * H_SZ) / 1024, 256, 0, stream>>>(w_hh, whh, 3 * H_SZ * H_SZ);
    conv_kernel<<<(H_SZ * D_SZ) / 1024, 256, 0, stream>>>(w_init, winit, H_SZ * D_SZ);
    conv_kernel<<<(B_SZ * D_SZ) / 1024, 256, 0, stream>>>(ev, evf, B_SZ * D_SZ);

    dim3 g0(H_SZ / 64, B_SZ / 128);  // (16, 32)
    h0_kernel<<<g0, 256, 0, stream>>>(evf, winit, b_init, hA);

    dim3 gs(H_SZ / 64, B_SZ / 128);  // (16, 32) = 512 blocks = 2 blocks/CU
    f16 *hc = hA, *hn = hB;
    for (int t = 0; t < T_SZ; ++t) {
        step_kernel<<<gs, 256, 0, stream>>>(hc, whh, b_hh, w_ih, b_ih, w_out,
                                            teach, hn, out, t);
        f16* tmp = hc; hc = hn; hn = tmp;
    }
    final_kernel<<<(B_SZ * 2 + 255) / 256, 256, 0, stream>>>(out, pos, b_out);
}